// Round 2
// baseline (251.536 us; speedup 1.0000x reference)
//
#include <hip/hip_runtime.h>
#include <hip/hip_bf16.h>
#include <math.h>

// Problem constants (fixed by setup_inputs)
#define BB 2
#define SS 1024
#define DD 128
#define MM 512
#define NH 4
#define HDIM 32
#define HID 512
#define LRC (0.1f/2048.0f)          // LR / (B*S)
#define SCALE 0.17677669529663687f  // 1/sqrt(32)

// ---------------------------------------------------------------------------
// K_A: fused surprise + T-partial.
//   S[bs,m] = ||x[bs,:]-mem[m,:]||  (computed in LDS, never written to global)
//   srow[m] += sum_bs S[bs,m]       (block-reduce + atomicAdd)
//   P3[(bx*16+by)][ml][d] = sum_{bs in tile} S[bs,m]*x[bs,d]  (per-block partial)
// grid (32 bs-blocks of 64, 16 m-blocks of 32), block 256
// ---------------------------------------------------------------------------
__global__ __launch_bounds__(256) void k_surpT(const float* __restrict__ x,
                                               const float* __restrict__ mem,
                                               float* __restrict__ P3,
                                               float* __restrict__ srow) {
  __shared__ float xt[128][68];   // x tile transposed [k][bs]
  __shared__ float mt[128][36];   // mem tile transposed [k][m]
  __shared__ float st[64][36];    // S tile [bs][m]
  __shared__ float red[32][17];   // per-m partial sums
  const int t = threadIdx.x;
  const int bs0 = blockIdx.x * 64;
  const int m0  = blockIdx.y * 32;

  for (int f4 = t; f4 < 2048; f4 += 256) {          // x tile 64x128 -> transposed
    int r = f4 >> 5, k4 = (f4 & 31) * 4;
    const float4 v = *reinterpret_cast<const float4*>(&x[(bs0 + r) * 128 + k4]);
    xt[k4+0][r] = v.x; xt[k4+1][r] = v.y; xt[k4+2][r] = v.z; xt[k4+3][r] = v.w;
  }
  for (int f4 = t; f4 < 1024; f4 += 256) {          // mem tile 32x128 -> transposed
    int r = f4 >> 5, k4 = (f4 & 31) * 4;
    const float4 v = *reinterpret_cast<const float4*>(&mem[(m0 + r) * 128 + k4]);
    mt[k4+0][r] = v.x; mt[k4+1][r] = v.y; mt[k4+2][r] = v.z; mt[k4+3][r] = v.w;
  }
  __syncthreads();

  // ---- S phase: each thread 4bs x 2m ----
  const int ti = t & 15, tj = t >> 4;
  const int r0 = ti * 4, j0 = tj * 2;
  float acc[4][2] = {};
  for (int k = 0; k < 128; ++k) {
    const float4 a  = *reinterpret_cast<const float4*>(&xt[k][r0]);
    const float2 m2 = *reinterpret_cast<const float2*>(&mt[k][j0]);
    float d;
    d = a.x - m2.x; acc[0][0] += d*d;
    d = a.y - m2.x; acc[1][0] += d*d;
    d = a.z - m2.x; acc[2][0] += d*d;
    d = a.w - m2.x; acc[3][0] += d*d;
    d = a.x - m2.y; acc[0][1] += d*d;
    d = a.y - m2.y; acc[1][1] += d*d;
    d = a.z - m2.y; acc[2][1] += d*d;
    d = a.w - m2.y; acc[3][1] += d*d;
  }
  float ps0 = 0.f, ps1 = 0.f;
  #pragma unroll
  for (int i = 0; i < 4; ++i) {
    const float s0 = sqrtf(acc[i][0]);
    const float s1 = sqrtf(acc[i][1]);
    float2 w2; w2.x = s0; w2.y = s1;
    *reinterpret_cast<float2*>(&st[r0 + i][j0]) = w2;
    ps0 += s0; ps1 += s1;
  }
  red[j0 + 0][ti] = ps0;
  red[j0 + 1][ti] = ps1;
  __syncthreads();
  if (t < 32) {
    float v = 0.f;
    #pragma unroll
    for (int i = 0; i < 16; ++i) v += red[t][i];
    atomicAdd(&srow[m0 + t], v);
  }

  // ---- T phase: partial T[ml][d] = sum_r st[r][ml] * xt[d][r] ----
  // thread: tti = m-quad (8x4 = 32 m), ttj = d lane, d = ttj + 32*j
  const int tti = t >> 5;
  const int ttj = t & 31;
  float tacc[4][4] = {};
  for (int r = 0; r < 64; ++r) {
    const float4 s4 = *reinterpret_cast<const float4*>(&st[r][tti * 4]);
    const float x0 = xt[ttj +  0][r];
    const float x1 = xt[ttj + 32][r];
    const float x2 = xt[ttj + 64][r];
    const float x3 = xt[ttj + 96][r];
    tacc[0][0] += s4.x*x0; tacc[0][1] += s4.x*x1; tacc[0][2] += s4.x*x2; tacc[0][3] += s4.x*x3;
    tacc[1][0] += s4.y*x0; tacc[1][1] += s4.y*x1; tacc[1][2] += s4.y*x2; tacc[1][3] += s4.y*x3;
    tacc[2][0] += s4.z*x0; tacc[2][1] += s4.z*x1; tacc[2][2] += s4.z*x2; tacc[2][3] += s4.z*x3;
    tacc[3][0] += s4.w*x0; tacc[3][1] += s4.w*x1; tacc[3][2] += s4.w*x2; tacc[3][3] += s4.w*x3;
  }
  const int pbase = (blockIdx.x * 16 + blockIdx.y) * 4096;
  #pragma unroll
  for (int i = 0; i < 4; ++i)
    #pragma unroll
    for (int j = 0; j < 4; ++j)
      P3[pbase + (tti * 4 + i) * 128 + ttj + 32 * j] = tacc[i][j];
}

// ---------------------------------------------------------------------------
// K_B: mem_new = mem + LRC*(T - srow*mem), T = sum of 32 partials
// ---------------------------------------------------------------------------
__global__ __launch_bounds__(256) void k_memnew(const float* __restrict__ mem,
                                                const float* __restrict__ P3,
                                                const float* __restrict__ srow,
                                                float* __restrict__ memn) {
  const int idx = blockIdx.x * 256 + threadIdx.x;   // 65536
  float ts = 0.f;
  #pragma unroll
  for (int c = 0; c < 32; ++c) ts += P3[c * 65536 + idx];
  const float mv = mem[idx];
  memn[idx] = mv + LRC * (ts - srow[idx >> 7] * mv);
}

// ---------------------------------------------------------------------------
// K_C: fused QKV projection. bx<64: q rows from x; bx<80: k; else: v.
// C[R,128] = A[R,128] @ W^T + b. tile 32r x 64c, block 256.
// ---------------------------------------------------------------------------
__global__ __launch_bounds__(256) void k_qkv(const float* __restrict__ x,
                                             const float* __restrict__ memn,
                                             const float* __restrict__ wq,
                                             const float* __restrict__ wk,
                                             const float* __restrict__ wv,
                                             const float* __restrict__ bq,
                                             const float* __restrict__ bk,
                                             const float* __restrict__ bv,
                                             float* __restrict__ qb,
                                             float* __restrict__ kb,
                                             float* __restrict__ vb) {
  __shared__ float At[128][36];
  __shared__ float Wt[128][68];
  const int t = threadIdx.x;
  const int bx = blockIdx.x;
  const float *A, *W, *bias; float* O; int rB;
  if (bx < 64)      { A = x;    W = wq; bias = bq; O = qb; rB = bx * 32; }
  else if (bx < 80) { A = memn; W = wk; bias = bk; O = kb; rB = (bx - 64) * 32; }
  else              { A = memn; W = wv; bias = bv; O = vb; rB = (bx - 80) * 32; }
  const int cB = blockIdx.y * 64;

  for (int f4 = t; f4 < 1024; f4 += 256) {
    int r = f4 >> 5, k4 = (f4 & 31) * 4;
    const float4 v = *reinterpret_cast<const float4*>(&A[(rB + r) * 128 + k4]);
    At[k4+0][r] = v.x; At[k4+1][r] = v.y; At[k4+2][r] = v.z; At[k4+3][r] = v.w;
  }
  for (int f4 = t; f4 < 2048; f4 += 256) {
    int r = f4 >> 5, k4 = (f4 & 31) * 4;
    const float4 v = *reinterpret_cast<const float4*>(&W[(cB + r) * 128 + k4]);
    Wt[k4+0][r] = v.x; Wt[k4+1][r] = v.y; Wt[k4+2][r] = v.z; Wt[k4+3][r] = v.w;
  }
  __syncthreads();
  const int ti = t & 7, tj = t >> 3;
  const int r0 = ti * 4, c0 = tj * 2;
  float acc[4][2] = {};
  for (int k = 0; k < 128; ++k) {
    const float4 a = *reinterpret_cast<const float4*>(&At[k][r0]);
    const float2 w = *reinterpret_cast<const float2*>(&Wt[k][c0]);
    acc[0][0] += a.x*w.x; acc[1][0] += a.y*w.x; acc[2][0] += a.z*w.x; acc[3][0] += a.w*w.x;
    acc[0][1] += a.x*w.y; acc[1][1] += a.y*w.y; acc[2][1] += a.z*w.y; acc[3][1] += a.w*w.y;
  }
  #pragma unroll
  for (int j = 0; j < 2; ++j) {
    const float bv_ = bias[cB + c0 + j];
    #pragma unroll
    for (int i = 0; i < 4; ++i)
      O[(rB + r0 + i) * 128 + cB + c0 + j] = acc[i][j] + bv_;
  }
}

// ---------------------------------------------------------------------------
// K_D: fused attention: scores (QK^T*scale) -> softmax -> PV, per (bh, s-tile 16)
// grid (64 s-tiles, 8 bh), block 256. Scores stay in LDS; normalization deferred.
// ---------------------------------------------------------------------------
__global__ __launch_bounds__(256) void k_attn(const float* __restrict__ qb,
                                              const float* __restrict__ kb,
                                              const float* __restrict__ vb,
                                              float* __restrict__ ctx) {
  __shared__ float ss[16][520];   // scores [s][m=512]
  __shared__ float kv[4608];      // kc: [k=32][m=128] pad 132  /  vc: [m=128][d=32] pad 36
  __shared__ float qt[32][20];    // q transposed [k][s], pre-scaled
  __shared__ float rowinv[16];
  const int t = threadIdx.x;
  const int sB = blockIdx.x * 16;
  const int bh = blockIdx.y;
  const int b = bh >> 2, h = bh & 3;

  if (t < 128) {                  // stage q tile 16x32 -> transposed, scaled
    int r = t >> 3, c4 = (t & 7) * 4;
    const float4 v = *reinterpret_cast<const float4*>(
        &qb[(b * SS + sB + r) * 128 + h * 32 + c4]);
    qt[c4+0][r] = v.x * SCALE; qt[c4+1][r] = v.y * SCALE;
    qt[c4+2][r] = v.z * SCALE; qt[c4+3][r] = v.w * SCALE;
  }

  // ---- scores: loop m-chunks of 128 ----
  const int sq = (t >> 6) * 4;    // s-quad (uniform per wave)
  const int m0 = (t & 63) * 2;    // m-pair within chunk
  for (int mc = 0; mc < MM; mc += 128) {
    __syncthreads();
    for (int f4 = t; f4 < 1024; f4 += 256) {   // stage k chunk transposed
      int r = f4 >> 3, c4 = (f4 & 7) * 4;
      const float4 v = *reinterpret_cast<const float4*>(
          &kb[(mc + r) * 128 + h * 32 + c4]);
      kv[(c4+0)*132 + r] = v.x; kv[(c4+1)*132 + r] = v.y;
      kv[(c4+2)*132 + r] = v.z; kv[(c4+3)*132 + r] = v.w;
    }
    __syncthreads();
    float acc[4][2] = {};
    for (int k = 0; k < 32; ++k) {
      const float4 q4 = *reinterpret_cast<const float4*>(&qt[k][sq]);
      const float2 k2 = *reinterpret_cast<const float2*>(&kv[k*132 + m0]);
      acc[0][0] += q4.x*k2.x; acc[0][1] += q4.x*k2.y;
      acc[1][0] += q4.y*k2.x; acc[1][1] += q4.y*k2.y;
      acc[2][0] += q4.z*k2.x; acc[2][1] += q4.z*k2.y;
      acc[3][0] += q4.w*k2.x; acc[3][1] += q4.w*k2.y;
    }
    #pragma unroll
    for (int i = 0; i < 4; ++i) {
      ss[sq+i][mc + m0 + 0] = acc[i][0];
      ss[sq+i][mc + m0 + 1] = acc[i][1];
    }
  }
  __syncthreads();

  // ---- softmax (exp only; 1/sum deferred): 4 waves x 4 rows ----
  {
    const int w = t >> 6, l = t & 63;
    #pragma unroll
    for (int rr = 0; rr < 4; ++rr) {
      const int row = w * 4 + rr;
      float4 v0 = *reinterpret_cast<float4*>(&ss[row][l*8]);
      float4 v1 = *reinterpret_cast<float4*>(&ss[row][l*8+4]);
      float mx = fmaxf(fmaxf(fmaxf(v0.x,v0.y),fmaxf(v0.z,v0.w)),
                       fmaxf(fmaxf(v1.x,v1.y),fmaxf(v1.z,v1.w)));
      #pragma unroll
      for (int off = 32; off; off >>= 1) mx = fmaxf(mx, __shfl_xor(mx, off));
      v0.x = __expf(v0.x - mx); v0.y = __expf(v0.y - mx);
      v0.z = __expf(v0.z - mx); v0.w = __expf(v0.w - mx);
      v1.x = __expf(v1.x - mx); v1.y = __expf(v1.y - mx);
      v1.z = __expf(v1.z - mx); v1.w = __expf(v1.w - mx);
      float sm = v0.x + v0.y + v0.z + v0.w + v1.x + v1.y + v1.z + v1.w;
      #pragma unroll
      for (int off = 32; off; off >>= 1) sm += __shfl_xor(sm, off);
      *reinterpret_cast<float4*>(&ss[row][l*8])   = v0;
      *reinterpret_cast<float4*>(&ss[row][l*8+4]) = v1;
      if (l == 0) rowinv[row] = 1.0f / sm;
    }
  }

  // ---- PV: ctx[s, d] = sum_m P[s,m] * v[m,d], then * rowinv ----
  const int d  = t & 31;
  const int s0 = (t >> 5) * 2;
  float a0 = 0.f, a1 = 0.f;
  for (int mc = 0; mc < MM; mc += 128) {
    __syncthreads();
    for (int f4 = t; f4 < 1024; f4 += 256) {   // stage v chunk [m][d]
      int r = f4 >> 3, c4 = (f4 & 7) * 4;
      *reinterpret_cast<float4*>(&kv[r*36 + c4]) =
          *reinterpret_cast<const float4*>(&vb[(mc + r) * 128 + h * 32 + c4]);
    }
    __syncthreads();
    for (int m4 = 0; m4 < 128; m4 += 4) {
      const float4 p0 = *reinterpret_cast<const float4*>(&ss[s0  ][mc+m4]);
      const float4 p1 = *reinterpret_cast<const float4*>(&ss[s0+1][mc+m4]);
      const float v0_ = kv[(m4+0)*36 + d];
      const float v1_ = kv[(m4+1)*36 + d];
      const float v2_ = kv[(m4+2)*36 + d];
      const float v3_ = kv[(m4+3)*36 + d];
      a0 += p0.x*v0_; a0 += p0.y*v1_; a0 += p0.z*v2_; a0 += p0.w*v3_;
      a1 += p1.x*v0_; a1 += p1.y*v1_; a1 += p1.z*v2_; a1 += p1.w*v3_;
    }
  }
  const float i0 = rowinv[s0], i1 = rowinv[s0+1];
  ctx[(b * SS + sB + s0    ) * 128 + h * 32 + d] = a0 * i0;
  ctx[(b * SS + sB + s0 + 1) * 128 + h * 32 + d] = a1 * i1;
}

// ---------------------------------------------------------------------------
// K_E/K_F (generic): C[R,N] = A[R,128] @ W[N,128]^T + b, optional relu
// tile 32r x 64c, block 256; grid (R/32, N/64)
// ---------------------------------------------------------------------------
__global__ __launch_bounds__(256) void k_proj(const float* __restrict__ A,
                                              const float* __restrict__ W,
                                              const float* __restrict__ bias,
                                              float* __restrict__ Cout,
                                              int N, int relu) {
  __shared__ float At[128][36];
  __shared__ float Wt[128][68];
  const int t = threadIdx.x;
  const int rB = blockIdx.x * 32, cB = blockIdx.y * 64;
  for (int f4 = t; f4 < 1024; f4 += 256) {
    int r = f4 >> 5, k4 = (f4 & 31) * 4;
    const float4 v = *reinterpret_cast<const float4*>(&A[(rB + r) * 128 + k4]);
    At[k4+0][r] = v.x; At[k4+1][r] = v.y; At[k4+2][r] = v.z; At[k4+3][r] = v.w;
  }
  for (int f4 = t; f4 < 2048; f4 += 256) {
    int r = f4 >> 5, k4 = (f4 & 31) * 4;
    const float4 v = *reinterpret_cast<const float4*>(&W[(cB + r) * 128 + k4]);
    Wt[k4+0][r] = v.x; Wt[k4+1][r] = v.y; Wt[k4+2][r] = v.z; Wt[k4+3][r] = v.w;
  }
  __syncthreads();
  const int ti = t & 7, tj = t >> 3;
  const int r0 = ti * 4, c0 = tj * 2;
  float acc[4][2] = {};
  for (int k = 0; k < 128; ++k) {
    const float4 a = *reinterpret_cast<const float4*>(&At[k][r0]);
    const float2 w = *reinterpret_cast<const float2*>(&Wt[k][c0]);
    acc[0][0] += a.x*w.x; acc[1][0] += a.y*w.x; acc[2][0] += a.z*w.x; acc[3][0] += a.w*w.x;
    acc[0][1] += a.x*w.y; acc[1][1] += a.y*w.y; acc[2][1] += a.z*w.y; acc[3][1] += a.w*w.y;
  }
  #pragma unroll
  for (int j = 0; j < 2; ++j) {
    const float bv = bias[cB + c0 + j];
    #pragma unroll
    for (int i = 0; i < 4; ++i) {
      float v = acc[i][j] + bv;
      if (relu) v = fmaxf(v, 0.f);
      Cout[(rB + r0 + i) * N + cB + c0 + j] = v;
    }
  }
}

// ---------------------------------------------------------------------------
extern "C" void kernel_launch(void* const* d_in, const int* in_sizes, int n_in,
                              void* d_out, int out_size, void* d_ws, size_t ws_size,
                              hipStream_t stream) {
  const float* x    = (const float*)d_in[0];
  const float* mem  = (const float*)d_in[1];
  const float* w_q  = (const float*)d_in[2];
  const float* w_k  = (const float*)d_in[3];
  const float* w_v  = (const float*)d_in[4];
  const float* b_q  = (const float*)d_in[5];
  const float* b_k  = (const float*)d_in[6];
  const float* b_v  = (const float*)d_in[7];
  const float* w_o  = (const float*)d_in[8];
  const float* b_o  = (const float*)d_in[9];
  const float* w_fc = (const float*)d_in[10];
  const float* b_fc = (const float*)d_in[11];
  float* out = (float*)d_out;

  float* ws = (float*)d_ws;
  // workspace layout (float offsets); total 3,080,704 floats = 12.3 MB
  float* srow  = ws + 0;        // [512]
  float* memn  = ws + 512;      // [512][128]
  float* qb    = ws + 66048;    // [2048][128]
  float* kb    = ws + 328192;   // [512][128]
  float* vb    = ws + 393728;   // [512][128]
  float* ctx   = ws + 459264;   // [2048][128]
  float* attno = ws + 721408;   // [2048][128]
  float* P3    = ws + 983552;   // [512 blocks][4096]

  hipMemsetAsync(srow, 0, 512 * sizeof(float), stream);

  k_surpT<<<dim3(32, 16), 256, 0, stream>>>(x, mem, P3, srow);
  k_memnew<<<dim3(256), 256, 0, stream>>>(mem, P3, srow, memn);
  k_qkv<<<dim3(96, 2), 256, 0, stream>>>(x, memn, w_q, w_k, w_v,
                                         b_q, b_k, b_v, qb, kb, vb);
  k_attn<<<dim3(64, 8), 256, 0, stream>>>(qb, kb, vb, ctx);
  k_proj<<<dim3(64, 2), 256, 0, stream>>>(ctx,   w_o,  b_o,  attno, 128, 0);
  k_proj<<<dim3(64, 8), 256, 0, stream>>>(attno, w_fc, b_fc, out,   512, 1);
}

// Round 3
// 107.054 us; speedup vs baseline: 2.3496x; 2.3496x over previous
//
#include <hip/hip_runtime.h>
#include <hip/hip_bf16.h>
#include <math.h>

// Problem constants (fixed by setup_inputs)
#define BB 2
#define SS 1024
#define DD 128
#define MM 512
#define NH 4
#define HDIM 32
#define HID 512
#define LRC (0.1f/2048.0f)          // LR / (B*S)
#define SCALE 0.17677669529663687f  // 1/sqrt(32)

// ---------------------------------------------------------------------------
// K_A: fused surprise + T-partial.
//   S[bs,m] = ||x[bs,:]-mem[m,:]||  (computed in LDS, never written to global)
//   srow[m] += sum_bs S[bs,m]       (block-reduce + atomicAdd)
//   P3[(bx*16+by)][ml][d] = sum_{bs in tile} S[bs,m]*x[bs,d]  (per-block partial)
// grid (32 bs-blocks of 64, 16 m-blocks of 32), block 256
// ---------------------------------------------------------------------------
__global__ __launch_bounds__(256) void k_surpT(const float* __restrict__ x,
                                               const float* __restrict__ mem,
                                               float* __restrict__ P3,
                                               float* __restrict__ srow) {
  __shared__ float xt[128][68];   // x tile transposed [k][bs]
  __shared__ float mt[128][36];   // mem tile transposed [k][m]
  __shared__ float st[64][36];    // S tile [bs][m]
  __shared__ float red[32][17];   // per-m partial sums
  const int t = threadIdx.x;
  const int bs0 = blockIdx.x * 64;
  const int m0  = blockIdx.y * 32;

  for (int f4 = t; f4 < 2048; f4 += 256) {          // x tile 64x128 -> transposed
    int r = f4 >> 5, k4 = (f4 & 31) * 4;
    const float4 v = *reinterpret_cast<const float4*>(&x[(bs0 + r) * 128 + k4]);
    xt[k4+0][r] = v.x; xt[k4+1][r] = v.y; xt[k4+2][r] = v.z; xt[k4+3][r] = v.w;
  }
  for (int f4 = t; f4 < 1024; f4 += 256) {          // mem tile 32x128 -> transposed
    int r = f4 >> 5, k4 = (f4 & 31) * 4;
    const float4 v = *reinterpret_cast<const float4*>(&mem[(m0 + r) * 128 + k4]);
    mt[k4+0][r] = v.x; mt[k4+1][r] = v.y; mt[k4+2][r] = v.z; mt[k4+3][r] = v.w;
  }
  __syncthreads();

  // ---- S phase: each thread 4bs x 2m ----
  const int ti = t & 15, tj = t >> 4;
  const int r0 = ti * 4, j0 = tj * 2;
  float acc[4][2] = {};
  for (int k = 0; k < 128; ++k) {
    const float4 a  = *reinterpret_cast<const float4*>(&xt[k][r0]);
    const float2 m2 = *reinterpret_cast<const float2*>(&mt[k][j0]);
    float d;
    d = a.x - m2.x; acc[0][0] += d*d;
    d = a.y - m2.x; acc[1][0] += d*d;
    d = a.z - m2.x; acc[2][0] += d*d;
    d = a.w - m2.x; acc[3][0] += d*d;
    d = a.x - m2.y; acc[0][1] += d*d;
    d = a.y - m2.y; acc[1][1] += d*d;
    d = a.z - m2.y; acc[2][1] += d*d;
    d = a.w - m2.y; acc[3][1] += d*d;
  }
  float ps0 = 0.f, ps1 = 0.f;
  #pragma unroll
  for (int i = 0; i < 4; ++i) {
    const float s0 = sqrtf(acc[i][0]);
    const float s1 = sqrtf(acc[i][1]);
    float2 w2; w2.x = s0; w2.y = s1;
    *reinterpret_cast<float2*>(&st[r0 + i][j0]) = w2;
    ps0 += s0; ps1 += s1;
  }
  red[j0 + 0][ti] = ps0;
  red[j0 + 1][ti] = ps1;
  __syncthreads();
  if (t < 32) {
    float v = 0.f;
    #pragma unroll
    for (int i = 0; i < 16; ++i) v += red[t][i];
    atomicAdd(&srow[m0 + t], v);
  }

  // ---- T phase: partial T[ml][d] = sum_r st[r][ml] * xt[d][r] ----
  const int tti = t >> 5;
  const int ttj = t & 31;
  float tacc[4][4] = {};
  for (int r = 0; r < 64; ++r) {
    const float4 s4 = *reinterpret_cast<const float4*>(&st[r][tti * 4]);
    const float x0 = xt[ttj +  0][r];
    const float x1 = xt[ttj + 32][r];
    const float x2 = xt[ttj + 64][r];
    const float x3 = xt[ttj + 96][r];
    tacc[0][0] += s4.x*x0; tacc[0][1] += s4.x*x1; tacc[0][2] += s4.x*x2; tacc[0][3] += s4.x*x3;
    tacc[1][0] += s4.y*x0; tacc[1][1] += s4.y*x1; tacc[1][2] += s4.y*x2; tacc[1][3] += s4.y*x3;
    tacc[2][0] += s4.z*x0; tacc[2][1] += s4.z*x1; tacc[2][2] += s4.z*x2; tacc[2][3] += s4.z*x3;
    tacc[3][0] += s4.w*x0; tacc[3][1] += s4.w*x1; tacc[3][2] += s4.w*x2; tacc[3][3] += s4.w*x3;
  }
  const int pbase = (blockIdx.x * 16 + blockIdx.y) * 4096;
  #pragma unroll
  for (int i = 0; i < 4; ++i)
    #pragma unroll
    for (int j = 0; j < 4; ++j)
      P3[pbase + (tti * 4 + i) * 128 + ttj + 32 * j] = tacc[i][j];
}

// ---------------------------------------------------------------------------
// K_B: mem_new = mem + LRC*(T - srow*mem), T = sum of 32 partials
// ---------------------------------------------------------------------------
__global__ __launch_bounds__(256) void k_memnew(const float* __restrict__ mem,
                                                const float* __restrict__ P3,
                                                const float* __restrict__ srow,
                                                float* __restrict__ memn) {
  const int idx = blockIdx.x * 256 + threadIdx.x;   // 65536
  float ts = 0.f;
  #pragma unroll
  for (int c = 0; c < 32; ++c) ts += P3[c * 65536 + idx];
  const float mv = mem[idx];
  memn[idx] = mv + LRC * (ts - srow[idx >> 7] * mv);
}

// ---------------------------------------------------------------------------
// K_C: fused QKV projection. bx<64: q rows from x; bx<80: k; else: v.
// ---------------------------------------------------------------------------
__global__ __launch_bounds__(256) void k_qkv(const float* __restrict__ x,
                                             const float* __restrict__ memn,
                                             const float* __restrict__ wq,
                                             const float* __restrict__ wk,
                                             const float* __restrict__ wv,
                                             const float* __restrict__ bq,
                                             const float* __restrict__ bk,
                                             const float* __restrict__ bv,
                                             float* __restrict__ qb,
                                             float* __restrict__ kb,
                                             float* __restrict__ vb) {
  __shared__ float At[128][36];
  __shared__ float Wt[128][68];
  const int t = threadIdx.x;
  const int bx = blockIdx.x;
  const float *A, *W, *bias; float* O; int rB;
  if (bx < 64)      { A = x;    W = wq; bias = bq; O = qb; rB = bx * 32; }
  else if (bx < 80) { A = memn; W = wk; bias = bk; O = kb; rB = (bx - 64) * 32; }
  else              { A = memn; W = wv; bias = bv; O = vb; rB = (bx - 80) * 32; }
  const int cB = blockIdx.y * 64;

  for (int f4 = t; f4 < 1024; f4 += 256) {
    int r = f4 >> 5, k4 = (f4 & 31) * 4;
    const float4 v = *reinterpret_cast<const float4*>(&A[(rB + r) * 128 + k4]);
    At[k4+0][r] = v.x; At[k4+1][r] = v.y; At[k4+2][r] = v.z; At[k4+3][r] = v.w;
  }
  for (int f4 = t; f4 < 2048; f4 += 256) {
    int r = f4 >> 5, k4 = (f4 & 31) * 4;
    const float4 v = *reinterpret_cast<const float4*>(&W[(cB + r) * 128 + k4]);
    Wt[k4+0][r] = v.x; Wt[k4+1][r] = v.y; Wt[k4+2][r] = v.z; Wt[k4+3][r] = v.w;
  }
  __syncthreads();
  const int ti = t & 7, tj = t >> 3;
  const int r0 = ti * 4, c0 = tj * 2;
  float acc[4][2] = {};
  for (int k = 0; k < 128; ++k) {
    const float4 a = *reinterpret_cast<const float4*>(&At[k][r0]);
    const float2 w = *reinterpret_cast<const float2*>(&Wt[k][c0]);
    acc[0][0] += a.x*w.x; acc[1][0] += a.y*w.x; acc[2][0] += a.z*w.x; acc[3][0] += a.w*w.x;
    acc[0][1] += a.x*w.y; acc[1][1] += a.y*w.y; acc[2][1] += a.z*w.y; acc[3][1] += a.w*w.y;
  }
  #pragma unroll
  for (int j = 0; j < 2; ++j) {
    const float bv_ = bias[cB + c0 + j];
    #pragma unroll
    for (int i = 0; i < 4; ++i)
      O[(rB + r0 + i) * 128 + cB + c0 + j] = acc[i][j] + bv_;
  }
}

// ---------------------------------------------------------------------------
// K5: scores[bh, s, m] = (q_head[s,:] . k_head[m,:]) * SCALE
// tile 64s x 64m, K=32; grid (16 sblk, 8 mblk, 8 bh), block 256
// ---------------------------------------------------------------------------
__global__ __launch_bounds__(256) void k_scores(const float* __restrict__ q,
                                                const float* __restrict__ kk,
                                                float* __restrict__ sc) {
  __shared__ float qt[32][68];
  __shared__ float kt[32][68];
  const int t = threadIdx.x;
  const int sB = blockIdx.x * 64;
  const int mB = blockIdx.y * 64;
  const int bh = blockIdx.z;
  const int b = bh >> 2, h = bh & 3;
  for (int f4 = t; f4 < 512; f4 += 256) {
    int r = f4 >> 3, k4 = (f4 & 7) * 4;
    const float4 v = *reinterpret_cast<const float4*>(
        &q[(b * SS + sB + r) * 128 + h * 32 + k4]);
    qt[k4+0][r] = v.x * SCALE; qt[k4+1][r] = v.y * SCALE;
    qt[k4+2][r] = v.z * SCALE; qt[k4+3][r] = v.w * SCALE;
  }
  for (int f4 = t; f4 < 512; f4 += 256) {
    int r = f4 >> 3, k4 = (f4 & 7) * 4;
    const float4 v = *reinterpret_cast<const float4*>(
        &kk[(mB + r) * 128 + h * 32 + k4]);
    kt[k4+0][r] = v.x; kt[k4+1][r] = v.y; kt[k4+2][r] = v.z; kt[k4+3][r] = v.w;
  }
  __syncthreads();
  const int ti = t & 15, tj = t >> 4;
  const int s0 = ti * 4, m0c = tj * 4;
  float acc[4][4] = {};
  for (int k = 0; k < 32; ++k) {
    const float4 a = *reinterpret_cast<const float4*>(&qt[k][s0]);
    const float4 w = *reinterpret_cast<const float4*>(&kt[k][m0c]);
    acc[0][0]+=a.x*w.x; acc[0][1]+=a.x*w.y; acc[0][2]+=a.x*w.z; acc[0][3]+=a.x*w.w;
    acc[1][0]+=a.y*w.x; acc[1][1]+=a.y*w.y; acc[1][2]+=a.y*w.z; acc[1][3]+=a.y*w.w;
    acc[2][0]+=a.z*w.x; acc[2][1]+=a.z*w.y; acc[2][2]+=a.z*w.z; acc[2][3]+=a.z*w.w;
    acc[3][0]+=a.w*w.x; acc[3][1]+=a.w*w.y; acc[3][2]+=a.w*w.z; acc[3][3]+=a.w*w.w;
  }
  #pragma unroll
  for (int i = 0; i < 4; ++i) {
    float4 o;
    o.x = acc[i][0]; o.y = acc[i][1]; o.z = acc[i][2]; o.w = acc[i][3];
    *reinterpret_cast<float4*>(
        &sc[(bh * SS + sB + s0 + i) * MM + mB + m0c]) = o;
  }
}

// ---------------------------------------------------------------------------
// K6: in-place row softmax over last dim (512). 1 wave per row.
// ---------------------------------------------------------------------------
__global__ __launch_bounds__(64) void k_softmax(float* __restrict__ sc) {
  const int row = blockIdx.x;       // 8192 rows
  const int l = threadIdx.x;
  float* p = &sc[(size_t)row * MM];
  float4 v0 = *reinterpret_cast<float4*>(&p[l * 8]);
  float4 v1 = *reinterpret_cast<float4*>(&p[l * 8 + 4]);
  float mx = fmaxf(fmaxf(fmaxf(v0.x, v0.y), fmaxf(v0.z, v0.w)),
                   fmaxf(fmaxf(v1.x, v1.y), fmaxf(v1.z, v1.w)));
  #pragma unroll
  for (int off = 32; off; off >>= 1) mx = fmaxf(mx, __shfl_xor(mx, off));
  v0.x = __expf(v0.x - mx); v0.y = __expf(v0.y - mx);
  v0.z = __expf(v0.z - mx); v0.w = __expf(v0.w - mx);
  v1.x = __expf(v1.x - mx); v1.y = __expf(v1.y - mx);
  v1.z = __expf(v1.z - mx); v1.w = __expf(v1.w - mx);
  float sm = v0.x + v0.y + v0.z + v0.w + v1.x + v1.y + v1.z + v1.w;
  #pragma unroll
  for (int off = 32; off; off >>= 1) sm += __shfl_xor(sm, off);
  const float inv = 1.f / sm;
  v0.x *= inv; v0.y *= inv; v0.z *= inv; v0.w *= inv;
  v1.x *= inv; v1.y *= inv; v1.z *= inv; v1.w *= inv;
  *reinterpret_cast<float4*>(&p[l * 8])     = v0;
  *reinterpret_cast<float4*>(&p[l * 8 + 4]) = v1;
}

// ---------------------------------------------------------------------------
// K7: ctx[bs, h*32+d] = sum_m attn[bh,s,m] * v[m, h*32+d]
// tile 64s x 32d (full head), K=512 in 4 chunks of 128
// grid (16 sblk, 8 bh), block 256
// ---------------------------------------------------------------------------
__global__ __launch_bounds__(256) void k_pv(const float* __restrict__ sc,
                                            const float* __restrict__ vv,
                                            float* __restrict__ ctx) {
  __shared__ float at[128][68];   // [m][s]
  __shared__ float vt[128][36];   // [m][d]
  const int t = threadIdx.x;
  const int sB = blockIdx.x * 64;
  const int bh = blockIdx.y;
  const int b = bh >> 2, h = bh & 3;
  const int ti = t & 15, tj = t >> 4;
  const int s0 = ti * 4, d0 = tj * 2;
  float acc[4][2] = {};
  for (int mc = 0; mc < MM; mc += 128) {
    __syncthreads();
    for (int f4 = t; f4 < 2048; f4 += 256) {   // attn tile 64 x 128 -> transposed
      int r = f4 >> 5, k4 = (f4 & 31) * 4;
      const float4 v = *reinterpret_cast<const float4*>(
          &sc[(bh * SS + sB + r) * MM + mc + k4]);
      at[k4+0][r] = v.x; at[k4+1][r] = v.y; at[k4+2][r] = v.z; at[k4+3][r] = v.w;
    }
    for (int f4 = t; f4 < 1024; f4 += 256) {   // v chunk 128 x 32
      int r = f4 >> 3, k4 = (f4 & 7) * 4;
      const float4 v = *reinterpret_cast<const float4*>(
          &vv[(mc + r) * 128 + h * 32 + k4]);
      *reinterpret_cast<float4*>(&vt[r][k4]) = v;
    }
    __syncthreads();
    for (int m = 0; m < 128; ++m) {
      const float4 a = *reinterpret_cast<const float4*>(&at[m][s0]);
      const float2 w = *reinterpret_cast<const float2*>(&vt[m][d0]);
      acc[0][0] += a.x*w.x; acc[1][0] += a.y*w.x; acc[2][0] += a.z*w.x; acc[3][0] += a.w*w.x;
      acc[0][1] += a.x*w.y; acc[1][1] += a.y*w.y; acc[2][1] += a.z*w.y; acc[3][1] += a.w*w.y;
    }
  }
  #pragma unroll
  for (int j = 0; j < 2; ++j)
    #pragma unroll
    for (int i = 0; i < 4; ++i)
      ctx[(b * SS + sB + s0 + i) * 128 + h * 32 + d0 + j] = acc[i][j];
}

// ---------------------------------------------------------------------------
// K_E/K_F (generic): C[R,N] = A[R,128] @ W[N,128]^T + b, optional relu
// ---------------------------------------------------------------------------
__global__ __launch_bounds__(256) void k_proj(const float* __restrict__ A,
                                              const float* __restrict__ W,
                                              const float* __restrict__ bias,
                                              float* __restrict__ Cout,
                                              int N, int relu) {
  __shared__ float At[128][36];
  __shared__ float Wt[128][68];
  const int t = threadIdx.x;
  const int rB = blockIdx.x * 32, cB = blockIdx.y * 64;
  for (int f4 = t; f4 < 1024; f4 += 256) {
    int r = f4 >> 5, k4 = (f4 & 31) * 4;
    const float4 v = *reinterpret_cast<const float4*>(&A[(rB + r) * 128 + k4]);
    At[k4+0][r] = v.x; At[k4+1][r] = v.y; At[k4+2][r] = v.z; At[k4+3][r] = v.w;
  }
  for (int f4 = t; f4 < 2048; f4 += 256) {
    int r = f4 >> 5, k4 = (f4 & 31) * 4;
    const float4 v = *reinterpret_cast<const float4*>(&W[(cB + r) * 128 + k4]);
    Wt[k4+0][r] = v.x; Wt[k4+1][r] = v.y; Wt[k4+2][r] = v.z; Wt[k4+3][r] = v.w;
  }
  __syncthreads();
  const int ti = t & 7, tj = t >> 3;
  const int r0 = ti * 4, c0 = tj * 2;
  float acc[4][2] = {};
  for (int k = 0; k < 128; ++k) {
    const float4 a = *reinterpret_cast<const float4*>(&At[k][r0]);
    const float2 w = *reinterpret_cast<const float2*>(&Wt[k][c0]);
    acc[0][0] += a.x*w.x; acc[1][0] += a.y*w.x; acc[2][0] += a.z*w.x; acc[3][0] += a.w*w.x;
    acc[0][1] += a.x*w.y; acc[1][1] += a.y*w.y; acc[2][1] += a.z*w.y; acc[3][1] += a.w*w.y;
  }
  #pragma unroll
  for (int j = 0; j < 2; ++j) {
    const float bv = bias[cB + c0 + j];
    #pragma unroll
    for (int i = 0; i < 4; ++i) {
      float v = acc[i][j] + bv;
      if (relu) v = fmaxf(v, 0.f);
      Cout[(rB + r0 + i) * N + cB + c0 + j] = v;
    }
  }
}

// ---------------------------------------------------------------------------
extern "C" void kernel_launch(void* const* d_in, const int* in_sizes, int n_in,
                              void* d_out, int out_size, void* d_ws, size_t ws_size,
                              hipStream_t stream) {
  const float* x    = (const float*)d_in[0];
  const float* mem  = (const float*)d_in[1];
  const float* w_q  = (const float*)d_in[2];
  const float* w_k  = (const float*)d_in[3];
  const float* w_v  = (const float*)d_in[4];
  const float* b_q  = (const float*)d_in[5];
  const float* b_k  = (const float*)d_in[6];
  const float* b_v  = (const float*)d_in[7];
  const float* w_o  = (const float*)d_in[8];
  const float* b_o  = (const float*)d_in[9];
  const float* w_fc = (const float*)d_in[10];
  const float* b_fc = (const float*)d_in[11];
  float* out = (float*)d_out;

  float* ws = (float*)d_ws;
  // workspace layout (float offsets); P3 aliased into sc (disjoint lifetimes)
  float* srow  = ws + 0;        // [512]
  float* memn  = ws + 512;      // [512][128]
  float* qb    = ws + 66048;    // [2048][128]
  float* kb    = ws + 328192;   // [512][128]
  float* vb    = ws + 393728;   // [512][128]
  float* ctx   = ws + 459264;   // [2048][128]
  float* attno = ws + 721408;   // [2048][128]
  float* big   = ws + 983552;   // max(P3 8MB, sc 16MB) -> 16MB
  float* P3    = big;           // [512 blocks][4096]   (used only before k_qkv)
  float* sc    = big;           // [8][1024][512]       (used only after k_qkv)

  hipMemsetAsync(srow, 0, 512 * sizeof(float), stream);

  k_surpT<<<dim3(32, 16), 256, 0, stream>>>(x, mem, P3, srow);
  k_memnew<<<dim3(256), 256, 0, stream>>>(mem, P3, srow, memn);
  k_qkv<<<dim3(96, 2), 256, 0, stream>>>(x, memn, w_q, w_k, w_v,
                                         b_q, b_k, b_v, qb, kb, vb);
  k_scores<<<dim3(16, 8, 8), 256, 0, stream>>>(qb, kb, sc);
  k_softmax<<<dim3(8192), 64, 0, stream>>>(sc);
  k_pv<<<dim3(16, 8), 256, 0, stream>>>(sc, vb, ctx);
  k_proj<<<dim3(64, 2), 256, 0, stream>>>(ctx,   w_o,  b_o,  attno, 128, 0);
  k_proj<<<dim3(64, 8), 256, 0, stream>>>(attno, w_fc, b_fc, out,   512, 1);
}

// Round 4
// 72.308 us; speedup vs baseline: 3.4787x; 1.4805x over previous
//
#include <hip/hip_runtime.h>
#include <hip/hip_bf16.h>
#include <math.h>

// Problem constants (fixed by setup_inputs)
#define SS 1024
#define MM 512
#define LRC (0.1f/2048.0f)          // LR / (B*S)
#define SCALE 0.17677669529663687f  // 1/sqrt(32)

typedef __attribute__((ext_vector_type(8))) short s8v;    // 8 bf16 (one MFMA frag)
typedef __attribute__((ext_vector_type(4))) float f32x4;
#define MFMA16(a, b, c) __builtin_amdgcn_mfma_f32_16x16x32_bf16(a, b, c, 0, 0, 0)

__device__ __forceinline__ unsigned short f2b(float f) {   // fp32 -> bf16 RNE
  union { float f; unsigned int u; } v; v.f = f;
  return (unsigned short)((v.u + 0x7FFFu + ((v.u >> 16) & 1u)) >> 16);
}

// ---------------------------------------------------------------------------
// K1 k_prep: xbf[2048][128], xT[128][2048], xnorm[2048]; membf[512][128],
// mnorm[512]; all weights -> bf16. grid 48 x 256.
// ---------------------------------------------------------------------------
__global__ __launch_bounds__(256) void k_prep(
    const float* __restrict__ x, const float* __restrict__ mem,
    const float* __restrict__ wq, const float* __restrict__ wk,
    const float* __restrict__ wv, const float* __restrict__ wo,
    const float* __restrict__ wfc,
    unsigned short* __restrict__ xbf, unsigned short* __restrict__ xT,
    float* __restrict__ xnorm, unsigned short* __restrict__ membf,
    float* __restrict__ mnorm,
    unsigned short* __restrict__ wqb, unsigned short* __restrict__ wkb,
    unsigned short* __restrict__ wvb, unsigned short* __restrict__ wob,
    unsigned short* __restrict__ wfcb) {
  const int t = threadIdx.x, bx = blockIdx.x;
  __shared__ float xl[64][132];
  if (bx < 32) {                       // x tiles: 64 rows each
    const int r0 = bx * 64;
    for (int i = t; i < 2048; i += 256) {
      int r = i >> 5, c4 = (i & 31) * 4;
      float4 v = *reinterpret_cast<const float4*>(&x[(r0 + r) * 128 + c4]);
      xl[r][c4] = v.x; xl[r][c4+1] = v.y; xl[r][c4+2] = v.z; xl[r][c4+3] = v.w;
      ushort4 u; u.x = f2b(v.x); u.y = f2b(v.y); u.z = f2b(v.z); u.w = f2b(v.w);
      *reinterpret_cast<ushort4*>(&xbf[(r0 + r) * 128 + c4]) = u;
    }
    __syncthreads();
    {                                  // row norms (fp32)
      int r = t >> 2, q = t & 3;
      float s = 0.f;
      #pragma unroll
      for (int j = 0; j < 32; ++j) { float v = xl[r][q * 32 + j]; s += v * v; }
      s += __shfl_xor(s, 1); s += __shfl_xor(s, 2);
      if (q == 0) xnorm[r0 + r] = s;
    }
    {                                  // transpose -> xT[d][bs]
      int d = t >> 1, hh = t & 1;
      #pragma unroll
      for (int j4 = 0; j4 < 32; j4 += 4) {
        ushort4 u;
        u.x = f2b(xl[hh*32 + j4    ][d]);
        u.y = f2b(xl[hh*32 + j4 + 1][d]);
        u.z = f2b(xl[hh*32 + j4 + 2][d]);
        u.w = f2b(xl[hh*32 + j4 + 3][d]);
        *reinterpret_cast<ushort4*>(&xT[d * 2048 + r0 + hh*32 + j4]) = u;
      }
    }
  } else if (bx < 40) {                // mem tiles
    const int r0 = (bx - 32) * 64;
    for (int i = t; i < 2048; i += 256) {
      int r = i >> 5, c4 = (i & 31) * 4;
      float4 v = *reinterpret_cast<const float4*>(&mem[(r0 + r) * 128 + c4]);
      xl[r][c4] = v.x; xl[r][c4+1] = v.y; xl[r][c4+2] = v.z; xl[r][c4+3] = v.w;
      ushort4 u; u.x = f2b(v.x); u.y = f2b(v.y); u.z = f2b(v.z); u.w = f2b(v.w);
      *reinterpret_cast<ushort4*>(&membf[(r0 + r) * 128 + c4]) = u;
    }
    __syncthreads();
    int r = t >> 2, q = t & 3;
    float s = 0.f;
    #pragma unroll
    for (int j = 0; j < 32; ++j) { float v = xl[r][q * 32 + j]; s += v * v; }
    s += __shfl_xor(s, 1); s += __shfl_xor(s, 2);
    if (q == 0) mnorm[r0 + r] = s;
  } else {                             // weight conversion
    const float* src; unsigned short* dst; int off = 0;
    if (bx == 40)      { src = wq;  dst = wqb; }
    else if (bx == 41) { src = wk;  dst = wkb; }
    else if (bx == 42) { src = wv;  dst = wvb; }
    else if (bx == 43) { src = wo;  dst = wob; }
    else               { src = wfc; dst = wfcb; off = (bx - 44) * 16384; }
    for (int i = t; i < 4096; i += 256) {
      float4 v = *reinterpret_cast<const float4*>(&src[off + i * 4]);
      ushort4 u; u.x = f2b(v.x); u.y = f2b(v.y); u.z = f2b(v.z); u.w = f2b(v.w);
      *reinterpret_cast<ushort4*>(&dst[off + i * 4]) = u;
    }
  }
}

// ---------------------------------------------------------------------------
// K2 k_surp: G = x@mem^T via MFMA; S = sqrt(xn + mn - 2G) -> STb[m][bs] bf16.
// grid (32 bs-blk of 64, 8 m-blk of 64) x 256 (4 waves; wave = 16 bs x 64 m)
// ---------------------------------------------------------------------------
__global__ __launch_bounds__(256) void k_surp(
    const unsigned short* __restrict__ xbf, const unsigned short* __restrict__ membf,
    const float* __restrict__ xnorm, const float* __restrict__ mnorm,
    unsigned short* __restrict__ STb) {
  const int t = threadIdx.x;
  const int bs0 = blockIdx.x * 64, m0 = blockIdx.y * 64;
  const int w = t >> 6, l = t & 63;
  const int kq = (l >> 4) * 8;
  const int arow = bs0 + w * 16 + (l & 15);
  f32x4 acc[4] = {};
  #pragma unroll
  for (int kc = 0; kc < 4; ++kc) {
    s8v a = *reinterpret_cast<const s8v*>(&xbf[arow * 128 + kc * 32 + kq]);
    #pragma unroll
    for (int mt = 0; mt < 4; ++mt) {
      s8v b = *reinterpret_cast<const s8v*>(&membf[(m0 + mt*16 + (l&15)) * 128 + kc*32 + kq]);
      acc[mt] = MFMA16(a, b, acc[mt]);
    }
  }
  const int r0 = bs0 + w * 16 + (l >> 4) * 4;
  float xn[4];
  #pragma unroll
  for (int i = 0; i < 4; ++i) xn[i] = xnorm[r0 + i];
  #pragma unroll
  for (int mt = 0; mt < 4; ++mt) {
    const int col = m0 + mt * 16 + (l & 15);
    const float mn = mnorm[col];
    ushort4 u;
    u.x = f2b(sqrtf(fmaxf(0.f, xn[0] + mn - 2.f * acc[mt][0])));
    u.y = f2b(sqrtf(fmaxf(0.f, xn[1] + mn - 2.f * acc[mt][1])));
    u.z = f2b(sqrtf(fmaxf(0.f, xn[2] + mn - 2.f * acc[mt][2])));
    u.w = f2b(sqrtf(fmaxf(0.f, xn[3] + mn - 2.f * acc[mt][3])));
    *reinterpret_cast<ushort4*>(&STb[col * 2048 + r0]) = u;
  }
}

// ---------------------------------------------------------------------------
// K3 k_qkv: bx<32: q = (x@wq^T+bq)*SCALE -> qbf.
// bx 32..63: k-blocks / bx 64..95: v-blocks: per 16-row m-strip:
//   T = ST@xT^T (K=2048) + srow (free from A-frag sums) -> memn (LDS only)
//   -> k = memn@wk^T+bk -> kbf[m][n];  v -> vT[n][m] (transposed write).
// ---------------------------------------------------------------------------
__global__ __launch_bounds__(256) void k_qkv(
    const unsigned short* __restrict__ xbf, const unsigned short* __restrict__ STb,
    const unsigned short* __restrict__ xT, const float* __restrict__ mem,
    const unsigned short* __restrict__ wqb, const unsigned short* __restrict__ wkb,
    const unsigned short* __restrict__ wvb,
    const float* __restrict__ bq, const float* __restrict__ bk,
    const float* __restrict__ bv,
    unsigned short* __restrict__ qbf, unsigned short* __restrict__ kbf,
    unsigned short* __restrict__ vT) {
  __shared__ float Tld[16][132];
  __shared__ float srowl[16];
  __shared__ unsigned short mnl[16][136];
  const int t = threadIdx.x, bx = blockIdx.x;
  const int w = t >> 6, l = t & 63;
  const int kq = (l >> 4) * 8;
  const int r0l = (l >> 4) * 4;
  if (bx < 32) {                       // ---- q path ----
    const int s0 = bx * 64;
    const int arow = s0 + w * 16 + (l & 15);
    f32x4 acc[8] = {};
    #pragma unroll
    for (int kc = 0; kc < 4; ++kc) {
      s8v a = *reinterpret_cast<const s8v*>(&xbf[arow * 128 + kc * 32 + kq]);
      #pragma unroll
      for (int nt = 0; nt < 8; ++nt) {
        s8v b = *reinterpret_cast<const s8v*>(&wqb[(nt*16 + (l&15)) * 128 + kc*32 + kq]);
        acc[nt] = MFMA16(a, b, acc[nt]);
      }
    }
    const int r0 = s0 + w * 16 + r0l;
    #pragma unroll
    for (int nt = 0; nt < 8; ++nt) {
      const int col = nt * 16 + (l & 15);
      const float bb = bq[col];
      #pragma unroll
      for (int i = 0; i < 4; ++i)
        qbf[(r0 + i) * 128 + col] = f2b((acc[nt][i] + bb) * SCALE);
    }
  } else {                             // ---- k/v path ----
    const bool isv = bx >= 64;
    const int m0 = (isv ? (bx - 64) : (bx - 32)) * 16;
    // T GEMM: wave w covers cols w*32..w*32+31; K = 2048
    f32x4 acc[2] = {};
    float ssum = 0.f;
    const int arow = m0 + (l & 15);
    #pragma unroll 4
    for (int kk = 0; kk < 64; ++kk) {
      s8v a = *reinterpret_cast<const s8v*>(&STb[arow * 2048 + kk * 32 + kq]);
      #pragma unroll
      for (int j = 0; j < 8; ++j) {    // srow partial from streamed S values
        union { unsigned int u; float f; } cv;
        cv.u = ((unsigned int)(unsigned short)a[j]) << 16;
        ssum += cv.f;
      }
      #pragma unroll
      for (int nt = 0; nt < 2; ++nt) {
        s8v b = *reinterpret_cast<const s8v*>(&xT[(w*32 + nt*16 + (l&15)) * 2048 + kk*32 + kq]);
        acc[nt] = MFMA16(a, b, acc[nt]);
      }
    }
    ssum += __shfl_xor(ssum, 16); ssum += __shfl_xor(ssum, 32);
    if (w == 0 && l < 16) srowl[l] = ssum;
    #pragma unroll
    for (int nt = 0; nt < 2; ++nt) {
      const int col = w * 32 + nt * 16 + (l & 15);
      #pragma unroll
      for (int i = 0; i < 4; ++i) Tld[r0l + i][col] = acc[nt][i];
    }
    __syncthreads();
    // memn = mem + LRC*(T - srow*mem)  (16x128, bf16 into LDS)
    #pragma unroll
    for (int i = 0; i < 8; ++i) {
      const int flat = t + 256 * i;
      const int r = flat >> 7, c = flat & 127;
      const float mv = mem[(m0 + r) * 128 + c];
      mnl[r][c] = f2b(mv + LRC * (Tld[r][c] - srowl[r] * mv));
    }
    __syncthreads();
    // projection: wave w covers cols w*32..w*32+31; K = 128, A from LDS
    const unsigned short* W = isv ? wvb : wkb;
    const float* bias = isv ? bv : bk;
    f32x4 pacc[2] = {};
    #pragma unroll
    for (int kc = 0; kc < 4; ++kc) {
      s8v a = *reinterpret_cast<const s8v*>(&mnl[l & 15][kc * 32 + kq]);
      #pragma unroll
      for (int nt = 0; nt < 2; ++nt) {
        s8v b = *reinterpret_cast<const s8v*>(&W[(w*32 + nt*16 + (l&15)) * 128 + kc*32 + kq]);
        pacc[nt] = MFMA16(a, b, pacc[nt]);
      }
    }
    #pragma unroll
    for (int nt = 0; nt < 2; ++nt) {
      const int col = w * 32 + nt * 16 + (l & 15);
      const float bb = bias[col];
      if (!isv) {
        #pragma unroll
        for (int i = 0; i < 4; ++i)
          kbf[(m0 + r0l + i) * 128 + col] = f2b(pacc[nt][i] + bb);
      } else {
        ushort4 u;
        u.x = f2b(pacc[nt][0] + bb); u.y = f2b(pacc[nt][1] + bb);
        u.z = f2b(pacc[nt][2] + bb); u.w = f2b(pacc[nt][3] + bb);
        *reinterpret_cast<ushort4*>(&vT[col * 512 + m0 + r0l]) = u;
      }
    }
  }
}

// ---------------------------------------------------------------------------
// K4 k_scores: scores (MFMA, K=32) + fused softmax -> P bf16 [8][1024][512]
// grid (16 s-blk of 64, 8 bh) x 256; wave = 16 s-rows x 512 m (32 m-tiles)
// ---------------------------------------------------------------------------
__global__ __launch_bounds__(256) void k_scores(
    const unsigned short* __restrict__ qbf, const unsigned short* __restrict__ kbf,
    unsigned short* __restrict__ P) {
  const int t = threadIdx.x;
  const int sB = blockIdx.x * 64;
  const int bh = blockIdx.y;
  const int b = bh >> 2, h = bh & 3;
  const int w = t >> 6, l = t & 63;
  const int kq = (l >> 4) * 8;
  const int arow = b * SS + sB + w * 16 + (l & 15);
  const s8v a = *reinterpret_cast<const s8v*>(&qbf[arow * 128 + h * 32 + kq]);
  f32x4 acc[32];
  #pragma unroll
  for (int mt = 0; mt < 32; ++mt) acc[mt] = f32x4{0.f, 0.f, 0.f, 0.f};
  #pragma unroll
  for (int mt = 0; mt < 32; ++mt) {
    s8v b2 = *reinterpret_cast<const s8v*>(&kbf[(mt*16 + (l&15)) * 128 + h*32 + kq]);
    acc[mt] = MFMA16(a, b2, acc[mt]);
  }
  const int prow0 = bh * SS + sB + w * 16 + (l >> 4) * 4;
  #pragma unroll
  for (int i = 0; i < 4; ++i) {
    float mx = acc[0][i];
    #pragma unroll
    for (int mt = 1; mt < 32; ++mt) mx = fmaxf(mx, acc[mt][i]);
    mx = fmaxf(mx, __shfl_xor(mx, 1));
    mx = fmaxf(mx, __shfl_xor(mx, 2));
    mx = fmaxf(mx, __shfl_xor(mx, 4));
    mx = fmaxf(mx, __shfl_xor(mx, 8));
    float sm = 0.f;
    #pragma unroll
    for (int mt = 0; mt < 32; ++mt) {
      float e = __expf(acc[mt][i] - mx); acc[mt][i] = e; sm += e;
    }
    sm += __shfl_xor(sm, 1); sm += __shfl_xor(sm, 2);
    sm += __shfl_xor(sm, 4); sm += __shfl_xor(sm, 8);
    const float inv = 1.f / sm;
    #pragma unroll
    for (int mt = 0; mt < 32; ++mt)
      P[(prow0 + i) * 512 + mt * 16 + (l & 15)] = f2b(acc[mt][i] * inv);
  }
}

// ---------------------------------------------------------------------------
// K5 k_pv: ctx = P @ vT^T (K=512). grid (16 s-blk, 8 bh) x 256.
// ---------------------------------------------------------------------------
__global__ __launch_bounds__(256) void k_pv(
    const unsigned short* __restrict__ P, const unsigned short* __restrict__ vT,
    unsigned short* __restrict__ ctx) {
  const int t = threadIdx.x;
  const int sB = blockIdx.x * 64;
  const int bh = blockIdx.y;
  const int b = bh >> 2, h = bh & 3;
  const int w = t >> 6, l = t & 63;
  const int kq = (l >> 4) * 8;
  const int arow = bh * SS + sB + w * 16 + (l & 15);
  f32x4 acc[2] = {};
  #pragma unroll 4
  for (int kk = 0; kk < 16; ++kk) {
    s8v a = *reinterpret_cast<const s8v*>(&P[arow * 512 + kk * 32 + kq]);
    #pragma unroll
    for (int nt = 0; nt < 2; ++nt) {
      s8v b2 = *reinterpret_cast<const s8v*>(&vT[(h*32 + nt*16 + (l&15)) * 512 + kk*32 + kq]);
      acc[nt] = MFMA16(a, b2, acc[nt]);
    }
  }
  const int r0 = b * SS + sB + w * 16 + (l >> 4) * 4;
  #pragma unroll
  for (int nt = 0; nt < 2; ++nt) {
    const int col = h * 32 + nt * 16 + (l & 15);
    #pragma unroll
    for (int i = 0; i < 4; ++i)
      ctx[(r0 + i) * 128 + col] = f2b(acc[nt][i]);
  }
}

// ---------------------------------------------------------------------------
// K6 k_wofc: attno = ctx@wo^T+bo (bf16, LDS) -> out = relu(attno@wfc^T+bfc)
// grid 64 x 256 (32 rows/block; wave = 16 rows x half the cols)
// ---------------------------------------------------------------------------
__global__ __launch_bounds__(256) void k_wofc(
    const unsigned short* __restrict__ ctx, const unsigned short* __restrict__ wob,
    const float* __restrict__ bo, const unsigned short* __restrict__ wfcb,
    const float* __restrict__ bfc, float* __restrict__ out) {
  __shared__ unsigned short al[32][136];
  const int t = threadIdx.x;
  const int rows0 = blockIdx.x * 32;
  const int w = t >> 6, l = t & 63;
  const int rt = w >> 1, ch = w & 1;
  const int kq = (l >> 4) * 8;
  {                                    // phase A: attno tile -> LDS
    const int arow = rows0 + rt * 16 + (l & 15);
    f32x4 acc[4] = {};
    #pragma unroll
    for (int kc = 0; kc < 4; ++kc) {
      s8v a = *reinterpret_cast<const s8v*>(&ctx[arow * 128 + kc * 32 + kq]);
      #pragma unroll
      for (int nt = 0; nt < 4; ++nt) {
        s8v b2 = *reinterpret_cast<const s8v*>(&wob[(ch*64 + nt*16 + (l&15)) * 128 + kc*32 + kq]);
        acc[nt] = MFMA16(a, b2, acc[nt]);
      }
    }
    const int rl0 = rt * 16 + (l >> 4) * 4;
    #pragma unroll
    for (int nt = 0; nt < 4; ++nt) {
      const int col = ch * 64 + nt * 16 + (l & 15);
      const float bb = bo[col];
      #pragma unroll
      for (int i = 0; i < 4; ++i) al[rl0 + i][col] = f2b(acc[nt][i] + bb);
    }
  }
  __syncthreads();
  {                                    // phase B: fc + relu -> out fp32
    f32x4 acc[16] = {};
    #pragma unroll
    for (int kc = 0; kc < 4; ++kc) {
      s8v a = *reinterpret_cast<const s8v*>(&al[rt * 16 + (l & 15)][kc * 32 + kq]);
      #pragma unroll
      for (int nt = 0; nt < 16; ++nt) {
        s8v b2 = *reinterpret_cast<const s8v*>(&wfcb[(ch*256 + nt*16 + (l&15)) * 128 + kc*32 + kq]);
        acc[nt] = MFMA16(a, b2, acc[nt]);
      }
    }
    const int r0 = rows0 + rt * 16 + (l >> 4) * 4;
    #pragma unroll
    for (int nt = 0; nt < 16; ++nt) {
      const int col = ch * 256 + nt * 16 + (l & 15);
      const float bb = bfc[col];
      #pragma unroll
      for (int i = 0; i < 4; ++i)
        out[(r0 + i) * 512 + col] = fmaxf(acc[nt][i] + bb, 0.f);
    }
  }
}

// ---------------------------------------------------------------------------
extern "C" void kernel_launch(void* const* d_in, const int* in_sizes, int n_in,
                              void* d_out, int out_size, void* d_ws, size_t ws_size,
                              hipStream_t stream) {
  const float* x    = (const float*)d_in[0];
  const float* mem  = (const float*)d_in[1];
  const float* w_q  = (const float*)d_in[2];
  const float* w_k  = (const float*)d_in[3];
  const float* w_v  = (const float*)d_in[4];
  const float* b_q  = (const float*)d_in[5];
  const float* b_k  = (const float*)d_in[6];
  const float* b_v  = (const float*)d_in[7];
  const float* w_o  = (const float*)d_in[8];
  const float* b_o  = (const float*)d_in[9];
  const float* w_fc = (const float*)d_in[10];
  const float* b_fc = (const float*)d_in[11];
  float* out = (float*)d_out;

  char* base = (char*)d_ws;            // ~12.6 MB total
  unsigned short* P     = (unsigned short*)(base);             // 8 MB
  unsigned short* STb   = (unsigned short*)(base + 8388608);   // 2 MB  S^T[m][bs]
  unsigned short* xbf   = (unsigned short*)(base + 10485760);  // 512 KB
  unsigned short* xT    = (unsigned short*)(base + 11010048);  // 512 KB
  unsigned short* qbf   = (unsigned short*)(base + 11534336);  // 512 KB
  unsigned short* ctx   = (unsigned short*)(base + 12058624);  // 512 KB
  unsigned short* kbf   = (unsigned short*)(base + 12582912);  // 128 KB
  unsigned short* vT    = (unsigned short*)(base + 12713984);  // 128 KB
  unsigned short* membf = (unsigned short*)(base + 12845056);  // 128 KB
  unsigned short* wfcb  = (unsigned short*)(base + 12976128);  // 128 KB
  unsigned short* wqb   = (unsigned short*)(base + 13107200);  // 32 KB
  unsigned short* wkb   = (unsigned short*)(base + 13139968);  // 32 KB
  unsigned short* wvb   = (unsigned short*)(base + 13172736);  // 32 KB
  unsigned short* wob   = (unsigned short*)(base + 13205504);  // 32 KB
  float* xnorm          = (float*)(base + 13238272);           // 8 KB
  float* mnorm          = (float*)(base + 13246464);           // 2 KB

  k_prep<<<48, 256, 0, stream>>>(x, mem, w_q, w_k, w_v, w_o, w_fc,
                                 xbf, xT, xnorm, membf, mnorm,
                                 wqb, wkb, wvb, wob, wfcb);
  k_surp<<<dim3(32, 8), 256, 0, stream>>>(xbf, membf, xnorm, mnorm, STb);
  k_qkv<<<96, 256, 0, stream>>>(xbf, STb, xT, mem, wqb, wkb, wvb,
                                b_q, b_k, b_v, qbf, kbf, vT);
  k_scores<<<dim3(16, 8), 256, 0, stream>>>(qbf, kbf, P);
  k_pv<<<dim3(16, 8), 256, 0, stream>>>(P, vT, ctx);
  k_wofc<<<64, 256, 0, stream>>>(ctx, wob, b_o, wfcb, b_fc, out);
}

// Round 6
// 58.906 us; speedup vs baseline: 4.2702x; 1.2275x over previous
//
#include <hip/hip_runtime.h>
#include <hip/hip_bf16.h>
#include <math.h>

// Problem constants (fixed by setup_inputs)
#define SS 1024
#define MM 512
#define LRC (0.1f/2048.0f)          // LR / (B*S)
#define SCALE 0.17677669529663687f  // 1/sqrt(32)

typedef __attribute__((ext_vector_type(8))) short s8v;    // 8 bf16 (one MFMA frag)
typedef __attribute__((ext_vector_type(4))) float f32x4;
#define MFMA16(a, b, c) __builtin_amdgcn_mfma_f32_16x16x32_bf16(a, b, c, 0, 0, 0)

__device__ __forceinline__ unsigned short f2b(float f) {   // fp32 -> bf16 RNE
  union { float f; unsigned int u; } v; v.f = f;
  return (unsigned short)((v.u + 0x7FFFu + ((v.u >> 16) & 1u)) >> 16);
}

// ---------------------------------------------------------------------------
// D1 k_p1 (295 blocks):
//  bx<256   : surprise tile (bs0=(bx&31)*64, m0=(bx>>5)*64): self-stage x,mem
//             fp32->LDS(bf16+norms); MFMA G=x@mem^T; S=sqrt(xn+mn-2G);
//             write STb[m][bs] bf16. by==0 blocks also emit xT[d][bs].
//  256..287 : q-projection (64 rows each): self-stage x,wq; q=(x@wq^T+bq)*SCALE
//  288..294 : weight conversion wk,wv,wo,wfc -> bf16
// ---------------------------------------------------------------------------
__global__ __launch_bounds__(256) void k_p1(
    const float* __restrict__ x, const float* __restrict__ mem,
    const float* __restrict__ wq, const float* __restrict__ wk,
    const float* __restrict__ wv, const float* __restrict__ wo,
    const float* __restrict__ wfc, const float* __restrict__ bq,
    unsigned short* __restrict__ STb, unsigned short* __restrict__ xT,
    unsigned short* __restrict__ qbf,
    unsigned short* __restrict__ wkb, unsigned short* __restrict__ wvb,
    unsigned short* __restrict__ wob, unsigned short* __restrict__ wfcb) {
  __shared__ alignas(16) char smem[69376];
  const int t = threadIdx.x, bx = blockIdx.x;
  const int w = t >> 6, l = t & 63;
  const int kq = (l >> 4) * 8;
  const int r0l = (l >> 4) * 4;

  if (bx < 256) {                      // ======== surprise tiles ========
    float (*xl)[132]          = reinterpret_cast<float (*)[132]>(smem);
    unsigned short (*xb)[136] = reinterpret_cast<unsigned short (*)[136]>(smem + 33792);
    unsigned short (*mb)[136] = reinterpret_cast<unsigned short (*)[136]>(smem + 51200);
    float* xn                 = reinterpret_cast<float*>(smem + 68608);
    float* mn                 = reinterpret_cast<float*>(smem + 68864);
    const int bs0 = (bx & 31) * 64, m0 = (bx >> 5) * 64;

    for (int i = t; i < 2048; i += 256) {          // stage x tile (fp32 + bf16)
      int r = i >> 5, c4 = (i & 31) * 4;
      float4 v = *reinterpret_cast<const float4*>(&x[(bs0 + r) * 128 + c4]);
      xl[r][c4] = v.x; xl[r][c4+1] = v.y; xl[r][c4+2] = v.z; xl[r][c4+3] = v.w;
      ushort4 u; u.x = f2b(v.x); u.y = f2b(v.y); u.z = f2b(v.z); u.w = f2b(v.w);
      *reinterpret_cast<ushort4*>(&xb[r][c4]) = u;
    }
    __syncthreads();
    {                                              // xnorm (fp32)
      int r = t >> 2, q = t & 3;
      float s = 0.f;
      #pragma unroll
      for (int j = 0; j < 32; ++j) { float v = xl[r][q * 32 + j]; s += v * v; }
      s += __shfl_xor(s, 1); s += __shfl_xor(s, 2);
      if (q == 0) xn[r] = s;
    }
    if ((bx >> 5) == 0) {                          // emit xT for D2
      int d = t >> 1, hh = t & 1;
      #pragma unroll
      for (int j4 = 0; j4 < 32; j4 += 4) {
        ushort4 u;
        u.x = xb[hh*32 + j4    ][d];
        u.y = xb[hh*32 + j4 + 1][d];
        u.z = xb[hh*32 + j4 + 2][d];
        u.w = xb[hh*32 + j4 + 3][d];
        *reinterpret_cast<ushort4*>(&xT[d * 2048 + bs0 + hh*32 + j4]) = u;
      }
    }
    __syncthreads();                               // xl free -> reuse for mem
    for (int i = t; i < 2048; i += 256) {
      int r = i >> 5, c4 = (i & 31) * 4;
      float4 v = *reinterpret_cast<const float4*>(&mem[(m0 + r) * 128 + c4]);
      xl[r][c4] = v.x; xl[r][c4+1] = v.y; xl[r][c4+2] = v.z; xl[r][c4+3] = v.w;
      ushort4 u; u.x = f2b(v.x); u.y = f2b(v.y); u.z = f2b(v.z); u.w = f2b(v.w);
      *reinterpret_cast<ushort4*>(&mb[r][c4]) = u;
    }
    __syncthreads();
    {                                              // mnorm (fp32)
      int r = t >> 2, q = t & 3;
      float s = 0.f;
      #pragma unroll
      for (int j = 0; j < 32; ++j) { float v = xl[r][q * 32 + j]; s += v * v; }
      s += __shfl_xor(s, 1); s += __shfl_xor(s, 2);
      if (q == 0) mn[r] = s;
    }
    __syncthreads();
    f32x4 acc[4] = {};                             // G = x@mem^T
    #pragma unroll
    for (int kc = 0; kc < 4; ++kc) {
      s8v a = *reinterpret_cast<const s8v*>(&xb[w*16 + (l&15)][kc*32 + kq]);
      #pragma unroll
      for (int mt = 0; mt < 4; ++mt) {
        s8v b = *reinterpret_cast<const s8v*>(&mb[mt*16 + (l&15)][kc*32 + kq]);
        acc[mt] = MFMA16(a, b, acc[mt]);
      }
    }
    const int r0g = bs0 + w * 16 + r0l;
    float xnr[4];
    #pragma unroll
    for (int i = 0; i < 4; ++i) xnr[i] = xn[w*16 + r0l + i];
    #pragma unroll
    for (int mt = 0; mt < 4; ++mt) {
      const int coll = mt * 16 + (l & 15);
      const float mnv = mn[coll];
      ushort4 u;
      u.x = f2b(sqrtf(fmaxf(0.f, xnr[0] + mnv - 2.f * acc[mt][0])));
      u.y = f2b(sqrtf(fmaxf(0.f, xnr[1] + mnv - 2.f * acc[mt][1])));
      u.z = f2b(sqrtf(fmaxf(0.f, xnr[2] + mnv - 2.f * acc[mt][2])));
      u.w = f2b(sqrtf(fmaxf(0.f, xnr[3] + mnv - 2.f * acc[mt][3])));
      *reinterpret_cast<ushort4*>(&STb[(m0 + coll) * 2048 + r0g]) = u;
    }
  } else if (bx < 288) {               // ======== q projection ========
    unsigned short (*xb)[136]  = reinterpret_cast<unsigned short (*)[136]>(smem);
    unsigned short (*wql)[136] = reinterpret_cast<unsigned short (*)[136]>(smem + 17408);
    const int s0 = (bx - 256) * 64;
    for (int i = t; i < 2048; i += 256) {
      int r = i >> 5, c4 = (i & 31) * 4;
      float4 v = *reinterpret_cast<const float4*>(&x[(s0 + r) * 128 + c4]);
      ushort4 u; u.x = f2b(v.x); u.y = f2b(v.y); u.z = f2b(v.z); u.w = f2b(v.w);
      *reinterpret_cast<ushort4*>(&xb[r][c4]) = u;
    }
    for (int i = t; i < 4096; i += 256) {
      int r = i >> 5, c4 = (i & 31) * 4;
      float4 v = *reinterpret_cast<const float4*>(&wq[r * 128 + c4]);
      ushort4 u; u.x = f2b(v.x); u.y = f2b(v.y); u.z = f2b(v.z); u.w = f2b(v.w);
      *reinterpret_cast<ushort4*>(&wql[r][c4]) = u;
    }
    __syncthreads();
    f32x4 acc[8] = {};
    #pragma unroll
    for (int kc = 0; kc < 4; ++kc) {
      s8v a = *reinterpret_cast<const s8v*>(&xb[w*16 + (l&15)][kc*32 + kq]);
      #pragma unroll
      for (int nt = 0; nt < 8; ++nt) {
        s8v b = *reinterpret_cast<const s8v*>(&wql[nt*16 + (l&15)][kc*32 + kq]);
        acc[nt] = MFMA16(a, b, acc[nt]);
      }
    }
    const int r0g = s0 + w * 16 + r0l;
    #pragma unroll
    for (int nt = 0; nt < 8; ++nt) {
      const int col = nt * 16 + (l & 15);
      const float bb = bq[col];
      #pragma unroll
      for (int i = 0; i < 4; ++i)
        qbf[(r0g + i) * 128 + col] = f2b((acc[nt][i] + bb) * SCALE);
    }
  } else {                             // ======== weight conversion ========
    const float* src; unsigned short* dst; int off = 0;
    if (bx == 288)      { src = wk;  dst = wkb; }
    else if (bx == 289) { src = wv;  dst = wvb; }
    else if (bx == 290) { src = wo;  dst = wob; }
    else                { src = wfc; dst = wfcb; off = (bx - 291) * 16384; }
    for (int i = t; i < 4096; i += 256) {
      float4 v = *reinterpret_cast<const float4*>(&src[off + i * 4]);
      ushort4 u; u.x = f2b(v.x); u.y = f2b(v.y); u.z = f2b(v.z); u.w = f2b(v.w);
      *reinterpret_cast<ushort4*>(&dst[off + i * 4]) = u;
    }
  }
}

// ---------------------------------------------------------------------------
// D2 k_p2 (32 blocks): per 16-row m-strip: T = S^T@x (K=2048, MFMA) with srow
// free from streamed S frags; memn in LDS; then k and v projections.
// ---------------------------------------------------------------------------
__global__ __launch_bounds__(256) void k_p2(
    const unsigned short* __restrict__ STb, const unsigned short* __restrict__ xT,
    const float* __restrict__ mem,
    const unsigned short* __restrict__ wkb, const unsigned short* __restrict__ wvb,
    const float* __restrict__ bk, const float* __restrict__ bv,
    unsigned short* __restrict__ kbf, unsigned short* __restrict__ vT) {
  __shared__ float Tld[16][132];
  __shared__ float srowl[16];
  __shared__ unsigned short mnl[16][136];
  const int t = threadIdx.x;
  const int w = t >> 6, l = t & 63;
  const int kq = (l >> 4) * 8;
  const int r0l = (l >> 4) * 4;
  const int m0 = blockIdx.x * 16;

  f32x4 acc[2] = {};
  float ssum = 0.f;
  const int arow = m0 + (l & 15);
  #pragma unroll 4
  for (int kk = 0; kk < 64; ++kk) {
    s8v a = *reinterpret_cast<const s8v*>(&STb[arow * 2048 + kk * 32 + kq]);
    #pragma unroll
    for (int j = 0; j < 8; ++j) {      // srow partial from streamed S values
      union { unsigned int u; float f; } cv;
      cv.u = ((unsigned int)(unsigned short)a[j]) << 16;
      ssum += cv.f;
    }
    #pragma unroll
    for (int nt = 0; nt < 2; ++nt) {
      s8v b = *reinterpret_cast<const s8v*>(&xT[(w*32 + nt*16 + (l&15)) * 2048 + kk*32 + kq]);
      acc[nt] = MFMA16(a, b, acc[nt]);
    }
  }
  ssum += __shfl_xor(ssum, 16); ssum += __shfl_xor(ssum, 32);
  if (w == 0 && l < 16) srowl[l] = ssum;
  #pragma unroll
  for (int nt = 0; nt < 2; ++nt) {
    const int col = w * 32 + nt * 16 + (l & 15);
    #pragma unroll
    for (int i = 0; i < 4; ++i) Tld[r0l + i][col] = acc[nt][i];
  }
  __syncthreads();
  #pragma unroll
  for (int i = 0; i < 8; ++i) {        // memn strip (bf16, LDS only)
    const int flat = t + 256 * i;
    const int r = flat >> 7, c = flat & 127;
    const float mv = mem[(m0 + r) * 128 + c];
    mnl[r][c] = f2b(mv + LRC * (Tld[r][c] - srowl[r] * mv));
  }
  __syncthreads();
  #pragma unroll
  for (int p = 0; p < 2; ++p) {        // p=0: k, p=1: v
    const unsigned short* W = p ? wvb : wkb;
    const float* bias = p ? bv : bk;
    f32x4 pacc[2] = {};
    #pragma unroll
    for (int kc = 0; kc < 4; ++kc) {
      s8v a = *reinterpret_cast<const s8v*>(&mnl[l & 15][kc * 32 + kq]);
      #pragma unroll
      for (int nt = 0; nt < 2; ++nt) {
        s8v b = *reinterpret_cast<const s8v*>(&W[(w*32 + nt*16 + (l&15)) * 128 + kc*32 + kq]);
        pacc[nt] = MFMA16(a, b, pacc[nt]);
      }
    }
    #pragma unroll
    for (int nt = 0; nt < 2; ++nt) {
      const int col = w * 32 + nt * 16 + (l & 15);
      const float bb = bias[col];
      if (p == 0) {
        #pragma unroll
        for (int i = 0; i < 4; ++i)
          kbf[(m0 + r0l + i) * 128 + col] = f2b(pacc[nt][i] + bb);
      } else {
        ushort4 u;
        u.x = f2b(pacc[nt][0] + bb); u.y = f2b(pacc[nt][1] + bb);
        u.z = f2b(pacc[nt][2] + bb); u.w = f2b(pacc[nt][3] + bb);
        *reinterpret_cast<ushort4*>(&vT[col * 512 + m0 + r0l]) = u;
      }
    }
  }
}

// ---------------------------------------------------------------------------
// D3 k_p3 (128 blocks): per 16 query rows, end-to-end:
//  scores+softmax (reg) -> P LDS -> PV -> ctx LDS -> wo -> attno LDS -> fc+relu
//  wave w handles head h=w in phases A/B; col-quarters in phases C/D.
// ---------------------------------------------------------------------------
__global__ __launch_bounds__(256) void k_p3(
    const unsigned short* __restrict__ qbf, const unsigned short* __restrict__ kbf,
    const unsigned short* __restrict__ vT, const unsigned short* __restrict__ wob,
    const unsigned short* __restrict__ wfcb, const float* __restrict__ bo,
    const float* __restrict__ bfc, float* __restrict__ out) {
  __shared__ alignas(16) char smem[75264];
  unsigned short (*Pl)[520] = reinterpret_cast<unsigned short (*)[520]>(smem);          // [64][520]: row = h*16+s
  unsigned short (*cl)[136] = reinterpret_cast<unsigned short (*)[136]>(smem + 66560);  // ctx [16][136]
  unsigned short (*al)[136] = reinterpret_cast<unsigned short (*)[136]>(smem + 70912);  // attno [16][136]
  const int t = threadIdx.x;
  const int w = t >> 6, l = t & 63;
  const int kq = (l >> 4) * 8;
  const int r0l = (l >> 4) * 4;
  const int r0 = blockIdx.x * 16;      // 16 query rows (bs index)

  {                                    // -- phase A: scores + softmax, head w --
    const int h = w;
    const s8v a = *reinterpret_cast<const s8v*>(&qbf[(r0 + (l & 15)) * 128 + h * 32 + kq]);
    f32x4 acc[32];
    #pragma unroll
    for (int mt = 0; mt < 32; ++mt) acc[mt] = f32x4{0.f, 0.f, 0.f, 0.f};
    #pragma unroll
    for (int mt = 0; mt < 32; ++mt) {
      s8v b2 = *reinterpret_cast<const s8v*>(&kbf[(mt*16 + (l&15)) * 128 + h*32 + kq]);
      acc[mt] = MFMA16(a, b2, acc[mt]);
    }
    #pragma unroll
    for (int i = 0; i < 4; ++i) {
      float mx = acc[0][i];
      #pragma unroll
      for (int mt = 1; mt < 32; ++mt) mx = fmaxf(mx, acc[mt][i]);
      mx = fmaxf(mx, __shfl_xor(mx, 1));
      mx = fmaxf(mx, __shfl_xor(mx, 2));
      mx = fmaxf(mx, __shfl_xor(mx, 4));
      mx = fmaxf(mx, __shfl_xor(mx, 8));
      float sm = 0.f;
      #pragma unroll
      for (int mt = 0; mt < 32; ++mt) {
        float e = __expf(acc[mt][i] - mx); acc[mt][i] = e; sm += e;
      }
      sm += __shfl_xor(sm, 1); sm += __shfl_xor(sm, 2);
      sm += __shfl_xor(sm, 4); sm += __shfl_xor(sm, 8);
      const float inv = 1.f / sm;
      #pragma unroll
      for (int mt = 0; mt < 32; ++mt)
        Pl[h * 16 + r0l + i][mt * 16 + (l & 15)] = f2b(acc[mt][i] * inv);
    }
  }
  __syncthreads();
  {                                    // -- phase B: PV, head w --
    const int h = w;
    f32x4 acc[2] = {};
    #pragma unroll 4
    for (int kk = 0; kk < 16; ++kk) {
      s8v a = *reinterpret_cast<const s8v*>(&Pl[h * 16 + (l & 15)][kk * 32 + kq]);
      #pragma unroll
      for (int nt = 0; nt < 2; ++nt) {
        s8v b2 = *reinterpret_cast<const s8v*>(&vT[(h*32 + nt*16 + (l&15)) * 512 + kk*32 + kq]);
        acc[nt] = MFMA16(a, b2, acc[nt]);
      }
    }
    #pragma unroll
    for (int nt = 0; nt < 2; ++nt) {
      const int col = h * 32 + nt * 16 + (l & 15);
      #pragma unroll
      for (int i = 0; i < 4; ++i) cl[r0l + i][col] = f2b(acc[nt][i]);
    }
  }
  __syncthreads();
  {                                    // -- phase C: attno = ctx@wo^T + bo --
    f32x4 acc[2] = {};
    #pragma unroll
    for (int kc = 0; kc < 4; ++kc) {
      s8v a = *reinterpret_cast<const s8v*>(&cl[l & 15][kc * 32 + kq]);
      #pragma unroll
      for (int nt = 0; nt < 2; ++nt) {
        s8v b2 = *reinterpret_cast<const s8v*>(&wob[(w*32 + nt*16 + (l&15)) * 128 + kc*32 + kq]);
        acc[nt] = MFMA16(a, b2, acc[nt]);
      }
    }
    #pragma unroll
    for (int nt = 0; nt < 2; ++nt) {
      const int col = w * 32 + nt * 16 + (l & 15);
      const float bb = bo[col];
      #pragma unroll
      for (int i = 0; i < 4; ++i) al[r0l + i][col] = f2b(acc[nt][i] + bb);
    }
  }
  __syncthreads();
  {                                    // -- phase D: out = relu(attno@wfc^T + bfc) --
    f32x4 acc[8] = {};
    #pragma unroll
    for (int kc = 0; kc < 4; ++kc) {
      s8v a = *reinterpret_cast<const s8v*>(&al[l & 15][kc * 32 + kq]);
      #pragma unroll
      for (int nt = 0; nt < 8; ++nt) {
        s8v b2 = *reinterpret_cast<const s8v*>(&wfcb[(w*128 + nt*16 + (l&15)) * 128 + kc*32 + kq]);
        acc[nt] = MFMA16(a, b2, acc[nt]);
      }
    }
    #pragma unroll
    for (int nt = 0; nt < 8; ++nt) {
      const int col = w * 128 + nt * 16 + (l & 15);
      const float bb = bfc[col];
      #pragma unroll
      for (int i = 0; i < 4; ++i)
        out[(r0 + r0l + i) * 512 + col] = fmaxf(acc[nt][i] + bb, 0.f);
    }
  }
}

// ---------------------------------------------------------------------------
extern "C" void kernel_launch(void* const* d_in, const int* in_sizes, int n_in,
                              void* d_out, int out_size, void* d_ws, size_t ws_size,
                              hipStream_t stream) {
  const float* x    = (const float*)d_in[0];
  const float* mem  = (const float*)d_in[1];
  const float* w_q  = (const float*)d_in[2];
  const float* w_k  = (const float*)d_in[3];
  const float* w_v  = (const float*)d_in[4];
  const float* b_q  = (const float*)d_in[5];
  const float* b_k  = (const float*)d_in[6];
  const float* b_v  = (const float*)d_in[7];
  const float* w_o  = (const float*)d_in[8];
  const float* b_o  = (const float*)d_in[9];
  const float* w_fc = (const float*)d_in[10];
  const float* b_fc = (const float*)d_in[11];
  float* out = (float*)d_out;

  char* base = (char*)d_ws;            // ~3.64 MB total
  unsigned short* STb  = (unsigned short*)(base);             // 2 MB   S^T[m][bs]
  unsigned short* xT   = (unsigned short*)(base + 2097152);   // 512 KB x^T[d][bs]
  unsigned short* qbf  = (unsigned short*)(base + 2621440);   // 512 KB
  unsigned short* kbf  = (unsigned short*)(base + 3145728);   // 128 KB
  unsigned short* vT   = (unsigned short*)(base + 3276800);   // 128 KB v^T[d][m]
  unsigned short* wkb  = (unsigned short*)(base + 3407872);   // 32 KB
  unsigned short* wvb  = (unsigned short*)(base + 3440640);   // 32 KB
  unsigned short* wob  = (unsigned short*)(base + 3473408);   // 32 KB
  unsigned short* wfcb = (unsigned short*)(base + 3506176);   // 128 KB

  k_p1<<<295, 256, 0, stream>>>(x, mem, w_q, w_k, w_v, w_o, w_fc, b_q,
                                STb, xT, qbf, wkb, wvb, wob, wfcb);
  k_p2<<<32, 256, 0, stream>>>(STb, xT, mem, wkb, wvb, b_k, b_v, kbf, vT);
  k_p3<<<128, 256, 0, stream>>>(qbf, kbf, vT, wob, wfcb, b_o, b_fc, out);
}